// Round 1
// baseline (245.310 us; speedup 1.0000x reference)
//
#include <hip/hip_runtime.h>
#include <math.h>

// PointLaplacianLoss: brute-force KNN (K=10) on point1, uniform Laplacian on
// both clouds with shared connectivity, mean L1 of the difference.
//
// Two-pass, index-free design:
//   Pass 1: per-thread branchless sorted top-10 distance list (19 v_min/v_max
//           per candidate, no divergence), 8 threads/query, merged in LDS to
//           the exact 10th-smallest distance tau per query.
//   Pass 2: re-scan with the bit-identical fmaf distance expression; accept
//           d2 <= tau (excluding self) and accumulate neighbor coord sums for
//           BOTH clouds + count. lap1-lap2 = (S1-S2)/cnt - (p1-p2).

constexpr int NPTS  = 8192;
constexpr int NB    = 2;
constexpr int KNN   = 10;
constexpr int T     = 8;          // candidate slices (sub-threads) per query
constexpr int QPB   = 32;         // queries per block
constexpr int TS    = 1024;       // candidates per LDS tile
constexpr int NTILES = NPTS / TS;
constexpr int BLOCK = QPB * T;    // 256 threads

__device__ __forceinline__ float dist2(float qx, float qy, float qz,
                                       float cx, float cy, float cz) {
    float dx = qx - cx, dy = qy - cy, dz = qz - cz;
    return fmaf(dx, dx, fmaf(dy, dy, dz * dz));
}

__global__ __launch_bounds__(BLOCK, 2)
void knn_lap(const float* __restrict__ p1, const float* __restrict__ p2,
             float* __restrict__ out)
{
    __shared__ float tileA[TS * 3];      // point1 candidate tile (AoS)
    __shared__ float tileB[TS * 3];      // point2 candidate tile (pass 2)
    __shared__ float mv[QPB * 81];       // merge buffer, stride 81 (odd -> no bank alias)
    __shared__ float tauS[QPB];
    __shared__ float parts[QPB * 57];    // partial sums, stride 57

    const int blocksPerBatch = NPTS / QPB;            // 256
    const int batch  = blockIdx.x / blocksPerBatch;
    const int qbase  = (blockIdx.x % blocksPerBatch) * QPB;
    const int t      = threadIdx.x;
    const int q_local = t % QPB;                      // wave = 2 sub-groups of 32
    const int sub     = t / QPB;
    const int query   = qbase + q_local;

    const float* P1 = p1 + (size_t)batch * NPTS * 3;
    const float* P2 = p2 + (size_t)batch * NPTS * 3;

    const float qx = P1[query * 3 + 0];
    const float qy = P1[query * 3 + 1];
    const float qz = P1[query * 3 + 2];

    const float INF = __builtin_huge_valf();
    float l[KNN];
#pragma unroll
    for (int k = 0; k < KNN; ++k) l[k] = INF;

    // ---------------- pass 1: per-thread top-K distances ----------------
    for (int tl = 0; tl < NTILES; ++tl) {
        __syncthreads();
        const float4* src = (const float4*)(P1 + tl * TS * 3);
        float4* dst = (float4*)tileA;
#pragma unroll
        for (int v = 0; v < 3; ++v) dst[v * BLOCK + t] = src[v * BLOCK + t];
        __syncthreads();
        const int jg0 = tl * TS;
#pragma unroll 4
        for (int i = 0; i < TS / T; ++i) {
            const int j = i * T + sub;
            const float cx = tileA[j * 3 + 0];
            const float cy = tileA[j * 3 + 1];
            const float cz = tileA[j * 3 + 2];
            float d2 = dist2(qx, qy, qz, cx, cy, cz);
            d2 = (jg0 + j == query) ? INF : d2;       // exclude self
            // branchless sorted insert (ascending l[0..9])
#pragma unroll
            for (int k = KNN - 1; k > 0; --k)
                l[k] = fminf(l[k], fmaxf(l[k - 1], d2));
            l[0] = fminf(l[0], d2);
        }
    }

    // ---------------- merge 8 partial lists -> tau per query ----------------
#pragma unroll
    for (int k = 0; k < KNN; ++k) mv[q_local * 81 + sub * KNN + k] = l[k];
    __syncthreads();
    if (t < QPB) {
        float m[KNN];
#pragma unroll
        for (int k = 0; k < KNN; ++k) m[k] = INF;
        for (int e = 0; e < T * KNN; ++e) {
            const float x = mv[t * 81 + e];
#pragma unroll
            for (int k = KNN - 1; k > 0; --k)
                m[k] = fminf(m[k], fmaxf(m[k - 1], x));
            m[0] = fminf(m[0], x);
        }
        tauS[t] = m[KNN - 1];   // exact 10th-smallest distance (self excluded)
    }
    __syncthreads();
    const float tau = tauS[q_local];

    // ---------------- pass 2: accumulate accepted neighbors ----------------
    float s1x = 0.f, s1y = 0.f, s1z = 0.f;
    float s2x = 0.f, s2y = 0.f, s2z = 0.f;
    int cnt = 0;
    for (int tl = 0; tl < NTILES; ++tl) {
        __syncthreads();
        const float4* srcA = (const float4*)(P1 + tl * TS * 3);
        const float4* srcB = (const float4*)(P2 + tl * TS * 3);
        float4* dstA = (float4*)tileA;
        float4* dstB = (float4*)tileB;
#pragma unroll
        for (int v = 0; v < 3; ++v) {
            dstA[v * BLOCK + t] = srcA[v * BLOCK + t];
            dstB[v * BLOCK + t] = srcB[v * BLOCK + t];
        }
        __syncthreads();
        const int jg0 = tl * TS;
#pragma unroll 4
        for (int i = 0; i < TS / T; ++i) {
            const int j = i * T + sub;
            const float cx = tileA[j * 3 + 0];
            const float cy = tileA[j * 3 + 1];
            const float cz = tileA[j * 3 + 2];
            const float d2 = dist2(qx, qy, qz, cx, cy, cz);
            const bool acc = (d2 <= tau) && (jg0 + j != query);
            if (acc) {   // ~10/8192 accept rate -> cheap skipped branch
                s1x += cx; s1y += cy; s1z += cz;
                s2x += tileB[j * 3 + 0];
                s2y += tileB[j * 3 + 1];
                s2z += tileB[j * 3 + 2];
                cnt++;
            }
        }
    }

    {
        float* pp = &parts[q_local * 57 + sub * 7];
        pp[0] = s1x; pp[1] = s1y; pp[2] = s1z;
        pp[3] = s2x; pp[4] = s2y; pp[5] = s2z;
        pp[6] = (float)cnt;
    }
    __syncthreads();

    // ---------------- per-query epilogue + block reduction ----------------
    if (t < QPB) {
        float a0 = 0, a1 = 0, a2 = 0, a3 = 0, a4 = 0, a5 = 0, a6 = 0;
        for (int s = 0; s < T; ++s) {
            const float* pp = &parts[t * 57 + s * 7];
            a0 += pp[0]; a1 += pp[1]; a2 += pp[2];
            a3 += pp[3]; a4 += pp[4]; a5 += pp[5]; a6 += pp[6];
        }
        const int q = qbase + t;            // == this thread's own query (sub==0)
        const float inv = 1.0f / a6;        // cnt (normally exactly 10)
        const float p2x = P2[q * 3 + 0];
        const float p2y = P2[q * 3 + 1];
        const float p2z = P2[q * 3 + 2];
        // qx,qy,qz of this thread are point1 coords of query qbase+t
        const float dx = (a0 - a3) * inv - (qx - p2x);
        const float dy = (a1 - a4) * inv - (qy - p2y);
        const float dz = (a2 - a5) * inv - (qz - p2z);
        float v = fabsf(dx) + fabsf(dy) + fabsf(dz);
        // reduce 32 active lanes (garbage from inactive sources never reaches lane 0)
#pragma unroll
        for (int off = 16; off > 0; off >>= 1) v += __shfl_down(v, off);
        if (t == 0) atomicAdd(out, v * (1.0f / (float)(NB * NPTS * 3)));
    }
}

extern "C" void kernel_launch(void* const* d_in, const int* in_sizes, int n_in,
                              void* d_out, int out_size, void* d_ws, size_t ws_size,
                              hipStream_t stream) {
    const float* p1 = (const float*)d_in[0];
    const float* p2 = (const float*)d_in[1];
    float* out = (float*)d_out;
    // d_out is poisoned 0xAA before every call; zero it for the atomic accumulate.
    hipMemsetAsync(out, 0, sizeof(float), stream);
    dim3 grid(NB * (NPTS / QPB));   // 512 blocks
    knn_lap<<<grid, BLOCK, 0, stream>>>(p1, p2, out);
}

// Round 2
// 150.837 us; speedup vs baseline: 1.6263x; 1.6263x over previous
//
#include <hip/hip_runtime.h>
#include <math.h>

// PointLaplacianLoss, single-pass index-in-key design.
//
// key = (asint(d2) & ~0x1FFF) | candidate_index  -- d2>=0 so int order ==
// float order; low 13 mantissa bits traded for the index (quantization 2^-10
// relative; near-tie swaps perturb the 49152-term mean by ~1e-5 each, bounded
// ~2e-3 total vs 1.67e-2 threshold). Stable-top_k tie-break (lower index
// first) falls out for free.
//
// Wave layout: lane = query (64 queries/wave-group), wave = candidate chunk.
// Candidates are wave-uniform -> scalar loads from a prepacked (x,y,z,|c|^2)
// float4 array in d_ws; the scan has NO LDS traffic and no barriers.
// Insert = branchless pair-merge network using v_min3_i32:
//   l[k] = min3(l[k], max(l[k-1],b0), max(l[k-2],b1))   (29 ops / 2 cands)

constexpr int NPTS  = 8192;
constexpr int NB    = 2;
constexpr int KNN   = 10;
constexpr int QPB   = 64;              // queries per block == lanes per wave
constexpr int WPB   = 8;               // waves per block (candidate chunks)
constexpr int BLOCK = QPB * WPB;       // 512 threads
constexpr int CHUNK = NPTS / WPB;      // 1024 candidates per wave
constexpr int MASK13 = 0xFFFFE000;     // keep sign+exp+10 mantissa bits

__global__ void prep_pack(const float* __restrict__ p, float4* __restrict__ w) {
    const int i = blockIdx.x * blockDim.x + threadIdx.x;
    if (i < NB * NPTS) {
        const float x = p[3 * i + 0], y = p[3 * i + 1], z = p[3 * i + 2];
        w[i] = make_float4(x, y, z, fmaf(x, x, fmaf(y, y, z * z)));
    }
}

// branchless merge of sorted pair {a,b} into ascending l[0..9], keep 10 smallest
__device__ __forceinline__ void ins2(int l[KNN], int a, int b) {
    const int b0 = min(a, b), b1 = max(a, b);
#pragma unroll
    for (int k = KNN - 1; k >= 2; --k)
        l[k] = min(l[k], min(max(l[k - 1], b0), max(l[k - 2], b1)));
    l[1] = min(l[1], min(max(l[0], b0), b1));
    l[0] = min(l[0], b0);
}

__global__ __launch_bounds__(BLOCK, 2)
void knn_lap(const float4* __restrict__ w1, const float* __restrict__ p2,
             float* __restrict__ out)
{
    __shared__ int mv[WPB * KNN * QPB];          // 20 KB

    const int blocksPerBatch = NPTS / QPB;       // 128
    const int batch = blockIdx.x / blocksPerBatch;
    const int qbase = (blockIdx.x % blocksPerBatch) * QPB;
    const int lane  = threadIdx.x & 63;
    const int wv    = __builtin_amdgcn_readfirstlane(threadIdx.x >> 6);
    const int query = qbase + lane;

    const float4* Wb = w1 + batch * NPTS;
    const float4 qp = Wb[query];                 // (x,y,z,|q|^2)
    const float m2x = -2.0f * qp.x, m2y = -2.0f * qp.y, m2z = -2.0f * qp.z;
    const float q2 = qp.w;
    const int IMAX = 0x7FFFFFFF;

    int l[KNN];
#pragma unroll
    for (int k = 0; k < KNN; ++k) l[k] = IMAX;

    // ------------- scan: wave-uniform candidates, zero LDS -------------
    const int c0 = wv * CHUNK;
    const float4* cand = Wb + c0;
#pragma unroll 4
    for (int i = 0; i < CHUNK; i += 2) {
        const float4 ca = cand[i];
        const float4 cb = cand[i + 1];
        const int ja = c0 + i, jb = ja + 1;
        const float da = fmaf(m2x, ca.x, fmaf(m2y, ca.y, fmaf(m2z, ca.z, ca.w + q2)));
        const float db = fmaf(m2x, cb.x, fmaf(m2y, cb.y, fmaf(m2z, cb.z, cb.w + q2)));
        int ka = (__float_as_int(da) & MASK13) | ja;
        int kb = (__float_as_int(db) & MASK13) | jb;
        ka = (ja == query) ? IMAX : ka;          // exclude self
        kb = (jb == query) ? IMAX : kb;
        ins2(l, ka, kb);
    }

    // ------------- merge 8 partial lists per query -------------
#pragma unroll
    for (int k = 0; k < KNN; ++k)
        mv[(wv * KNN + k) * QPB + lane] = l[k];
    __syncthreads();

    if (threadIdx.x < QPB) {                     // wave 0: lane == query
        int m[KNN];
#pragma unroll
        for (int k = 0; k < KNN; ++k) m[k] = IMAX;
#pragma unroll 4
        for (int e = 0; e < WPB * KNN; e += 2)
            ins2(m, mv[e * QPB + lane], mv[(e + 1) * QPB + lane]);

        // ------------- epilogue: gather 10 neighbors, lap diff -------------
        const float* P2b = p2 + (size_t)batch * NPTS * 3;
        float s1x = 0, s1y = 0, s1z = 0, s2x = 0, s2y = 0, s2z = 0;
#pragma unroll
        for (int k = 0; k < KNN; ++k) {
            const int j = m[k] & (NPTS - 1);
            const float4 c = Wb[j];
            s1x += c.x; s1y += c.y; s1z += c.z;
            s2x += P2b[3 * j + 0];
            s2y += P2b[3 * j + 1];
            s2z += P2b[3 * j + 2];
        }
        const float p2x = P2b[3 * query + 0];
        const float p2y = P2b[3 * query + 1];
        const float p2z = P2b[3 * query + 2];
        const float dx = (s1x * 0.1f - qp.x) - (s2x * 0.1f - p2x);
        const float dy = (s1y * 0.1f - qp.y) - (s2y * 0.1f - p2y);
        const float dz = (s1z * 0.1f - qp.z) - (s2z * 0.1f - p2z);
        float v = fabsf(dx) + fabsf(dy) + fabsf(dz);
#pragma unroll
        for (int off = 32; off >= 1; off >>= 1) v += __shfl_down(v, off);
        if (threadIdx.x == 0)
            atomicAdd(out, v * (1.0f / (float)(NB * NPTS * 3)));
    }
}

extern "C" void kernel_launch(void* const* d_in, const int* in_sizes, int n_in,
                              void* d_out, int out_size, void* d_ws, size_t ws_size,
                              hipStream_t stream) {
    const float* p1 = (const float*)d_in[0];
    const float* p2 = (const float*)d_in[1];
    float* out = (float*)d_out;
    float4* w1 = (float4*)d_ws;                  // NB*NPTS float4 = 256 KB

    hipMemsetAsync(out, 0, sizeof(float), stream);
    prep_pack<<<(NB * NPTS + 255) / 256, 256, 0, stream>>>(p1, w1);
    knn_lap<<<NB * (NPTS / QPB), BLOCK, 0, stream>>>(w1, p2, out);
}